// Round 10
// baseline (71.555 us; speedup 1.0000x reference)
//
#include <hip/hip_runtime.h>
#include <math.h>

#define BB 16384
#define NSTEPS 32
#define HH 128
#define DTF (1.0f/32.0f)
#define SCALE 2.88539008177792681f   // 2*log2(e):  e^{2x} = 2^{SCALE*x}
#define LOG2E 1.44269504088896340f

typedef float v2f  __attribute__((ext_vector_type(2)));
typedef float v16f __attribute__((ext_vector_type(16)));
typedef unsigned int v2u __attribute__((ext_vector_type(2)));

// compile-time slice: element-pair k of a v16f (even-aligned -> SGPR pair)
#define SL(v,k) (__builtin_shufflevector((v),(v),2*(k),2*(k)+1))

__device__ __forceinline__ v2f pk_fma(v2f a, v2f b, v2f c) {
    return __builtin_elementwise_fma(a, b, c);   // -> v_pk_fma_f32
}

// packed fast reciprocal: bit-trick estimate + 1 Newton. Valid x in [1, ~1e38].
__device__ __forceinline__ v2f pk_rcp1(v2f x) {
    v2u xb; __builtin_memcpy(&xb, &x, 8);
    v2u yb = (v2u){0x7EF311C3u, 0x7EF311C3u} - xb;
    v2f y;  __builtin_memcpy(&y, &yb, 8);
    v2f u = pk_fma(-x, y, (v2f){2.0f, 2.0f});    // 2 - x*y
    return y * u;
}

__device__ __forceinline__ float fexp2(float x) {
#if __has_builtin(__builtin_amdgcn_exp2f)
    return __builtin_amdgcn_exp2f(x);
#else
    float r; asm("v_exp_f32 %0, %1" : "=v"(r) : "v"(x)); return r;
#endif
}
__device__ __forceinline__ float frcp(float x) {
#if __has_builtin(__builtin_amdgcn_rcpf)
    return __builtin_amdgcn_rcpf(x);
#else
    float r; asm("v_rcp_f32 %0, %1" : "=v"(r) : "v"(x)); return r;
#endif
}
__device__ __forceinline__ float frsq(float x) {
#if __has_builtin(__builtin_amdgcn_rsqf)
    return __builtin_amdgcn_rsqf(x);
#else
    float r; asm("v_rsq_f32 %0, %1" : "=v"(r) : "v"(x)); return r;
#endif
}

// ---------------------------------------------------------------------------
// Transform kernel (R8 layout). Per unit-PAIR (j,j+1) at step i, 32 floats:
//  g-record [0..15]:  w0p w1p w2p w3p gbp g20p g21p g22p   (pairs, scaled)
//  j-record [16..31]: jw0p jw1p jw2p jw3p jbp jW2p cpp cmp
// ---------------------------------------------------------------------------
__global__ __launch_bounds__(HH) void xform_kernel(
    const float* __restrict__ gW1, const float* __restrict__ gb1,
    const float* __restrict__ gW2, const float* __restrict__ gb2,
    const float* __restrict__ jW1, const float* __restrict__ jb1,
    const float* __restrict__ jW2,
    float* __restrict__ recA, float* __restrict__ G)
{
    const int i = blockIdx.x;    // step
    const int j = threadIdx.x;   // hidden unit
    const int pair = j >> 1;
    const int ln   = j & 1;
    float* r = recA + ((size_t)i*64 + pair)*32;

    const float* gw = gW1 + (size_t)(i*HH + j)*4;
    const float* jw = jW1 + (size_t)(i*HH + j)*4;
    float jw0 = jw[0];
    float g20 = gW2[i*3*HH + 0*HH + j];
    float g21 = gW2[i*3*HH + 1*HH + j];
    float g22 = gW2[i*3*HH + 2*HH + j];

    r[ 0+ln] = SCALE*gw[0];
    r[ 2+ln] = SCALE*gw[1];
    r[ 4+ln] = SCALE*gw[2];
    r[ 6+ln] = SCALE*gw[3];
    r[ 8+ln] = SCALE*gb1[i*HH + j];
    r[10+ln] = -2.0f*g20;
    r[12+ln] = -2.0f*g21;
    r[14+ln] = -2.0f*g22;

    r[16+ln] = SCALE*jw0;
    r[18+ln] = SCALE*jw[1];
    r[20+ln] = SCALE*jw[2];
    r[22+ln] = SCALE*jw[3];
    r[24+ln] = SCALE*jb1[i*HH + j];
    r[26+ln] = -2.0f*jW2[i*HH + j];
    r[28+ln] = exp2f( SCALE*jw0);
    r[30+ln] = exp2f(-SCALE*jw0);

    __shared__ float sh[3*HH];
    sh[j] = g20; sh[HH + j] = g21; sh[2*HH + j] = g22;
    __syncthreads();
    for (int off = 64; off >= 1; off >>= 1) {
        if (j < off) {
            sh[j]      += sh[j + off];
            sh[HH + j] += sh[HH + j + off];
            sh[2*HH+j] += sh[2*HH + j + off];
        }
        __syncthreads();
    }
    if (j < 3) G[i*4 + j] = gb2[i*3 + j] + sh[j*HH];
}

// ---------------------------------------------------------------------------
// Main kernel. Block = 512 threads = 64 batch slots x 8 j-eighths (each wave
// one eighth -> je wave-uniform via readfirstlane -> scalar weight loads).
// Each thread: 8 unit-pairs (fully unrolled). Eighths combine via LDS.
// 8192 blocks x 8 waves = 65536 short waves; 4 blocks/CU = full residency.
// ---------------------------------------------------------------------------
__global__ __launch_bounds__(512) void step_kernel(
    const float* __restrict__ N, const float* __restrict__ X,
    const float* __restrict__ T, const float* __restrict__ dB,
    const float* __restrict__ recA, const float* __restrict__ G,
    float* __restrict__ C)
{
    const int tid  = threadIdx.x;
    const int i    = blockIdx.x >> 8;          // step (block-uniform)
    const int bblk = blockIdx.x & 255;
    const int bl   = tid & 63;                 // local batch slot
    const int je   = __builtin_amdgcn_readfirstlane(tid >> 6);  // eighth -> SGPR
    const int b    = bblk*64 + bl;
    const int ib   = i*BB + b;

    const float Ni = N[ib];
    const float x0 = X[(size_t)ib*3 + 0], x1 = X[(size_t)ib*3 + 1], x2 = X[(size_t)ib*3 + 2];

    // eighth e covers unit-pairs [e*8, e*8+8): 8 x 32 floats = 16 v16f
    const v16f* rec16 = (const v16f*)(recA + (size_t)i*HH*16 + (size_t)je*256);

    const v2f Niv  = {Ni, Ni};
    const v2f x0v  = {x0, x0};
    const v2f x1v  = {x1, x1};
    const v2f x2v  = {x2, x2};
    const v2f onev = {1.0f, 1.0f};
    const v2f c25v = {25.0f, 25.0f};

    v2f ga0 = {0.f,0.f}, ga1 = {0.f,0.f}, ga2 = {0.f,0.f};
    v2f a0  = {0.f,0.f}, aP  = {0.f,0.f}, aM  = {0.f,0.f};

#pragma unroll
    for (int t = 0; t < 8; ++t) {
        const v16f Rg = rec16[2*t + 0];   // g-record
        const v16f Rj = rec16[2*t + 1];   // j-record

        // ---- g-MLP, units (2t, 2t+1) packed ----
        v2f ag = SL(Rg,4);
        ag = pk_fma(SL(Rg,0), Niv, ag);
        ag = pk_fma(SL(Rg,1), x0v, ag);
        ag = pk_fma(SL(Rg,2), x1v, ag);
        ag = pk_fma(SL(Rg,3), x2v, ag);
        ag = __builtin_elementwise_min(ag, c25v); // keep exp2 finite (rcp1 domain)
        v2f eg; eg.x = fexp2(ag.x); eg.y = fexp2(ag.y);
        v2f rg = pk_rcp1(eg + onev);
        ga0 = pk_fma(SL(Rg,5), rg, ga0);
        ga1 = pk_fma(SL(Rg,6), rg, ga1);
        ga2 = pk_fma(SL(Rg,7), rg, ga2);

        // ---- j-MLP, units (2t, 2t+1) packed, 3 N-shifts share one exp ----
        v2f aj = SL(Rj,4);
        aj = pk_fma(SL(Rj,0), Niv, aj);
        aj = pk_fma(SL(Rj,1), x0v, aj);
        aj = pk_fma(SL(Rj,2), x1v, aj);
        aj = pk_fma(SL(Rj,3), x2v, aj);
        aj = __builtin_elementwise_min(aj, c25v);
        v2f ej; ej.x = fexp2(aj.x); ej.y = fexp2(aj.y);
        v2f r0 = pk_rcp1(ej + onev);
        v2f rp = pk_rcp1(pk_fma(SL(Rj,6), ej, onev));
        v2f rm = pk_rcp1(pk_fma(SL(Rj,7), ej, onev));
        const v2f w2p = SL(Rj,5);
        a0 = pk_fma(w2p, r0, a0);
        aP = pk_fma(w2p, rp, aP);
        aM = pk_fma(w2p, rm, aM);
    }

    // horizontal: even+odd unit lanes
    const float hga0 = ga0.x + ga0.y;
    const float hga1 = ga1.x + ga1.y;
    const float hga2 = ga2.x + ga2.y;
    const float ha0  = a0.x  + a0.y;
    const float haP  = aP.x  + aP.y;
    const float haM  = aM.x  + aM.y;

    // combine 8 eighth-partials: eighths 1..7 write, eighth 0 reduces
    __shared__ float sh[7][6][64];
    if (je) {
        float* s = &sh[je-1][0][bl];
        s[0*64] = hga0; s[1*64] = hga1; s[2*64] = hga2;
        s[3*64] = ha0;  s[4*64] = haP;  s[5*64] = haM;
    }
    __syncthreads();
    if (!je) {
        float v0 = hga0, v1 = hga1, v2 = hga2;
        float v3 = ha0,  v4 = haP,  v5 = haM;
#pragma unroll
        for (int q = 0; q < 7; ++q) {
            v0 += sh[q][0][bl]; v1 += sh[q][1][bl]; v2 += sh[q][2][bl];
            v3 += sh[q][3][bl]; v4 += sh[q][4][bl]; v5 += sh[q][5][bl];
        }
        const float g0 = G[i*4 + 0] + v0;
        const float g1 = G[i*4 + 1] + v1;
        const float g2 = G[i*4 + 2] + v2;

        const float Np1 = N[ib + BB];
        const float d0 = dB[(size_t)ib*3 + 0], d1 = dB[(size_t)ib*3 + 1], d2 = dB[(size_t)ib*3 + 2];
        const float ti = T[i];

        const float gdx = g0*x0 + g1*x1 + g2*x2;          // grad_u . x
        const float ss  = x0*x0 + x1*x1 + x2*x2;          // x . x
        const float gdB = g0*d0 + g1*d1 + g2*d2;          // grad_u . dB
        const float xdB = x0*d0 + x1*d1 + x2*d2;          // x . dB

        const float k = 1.41421356237309505f * frsq(fmaf(0.1f*Ni, Ni, 1.0f));
        // kg^T (I+o)(I-o) dB = k*(g.dB - (x.x)*(g.x)*(x.dB))
        const float grad_bmm = k * (gdB - ss*gdx*xdB);

        const float dp = v4 - v3;
        const float dm = v5 - v3;

        // alpha = 0.3*sig(0.1 N), beta = 0.2*(1-sig(0.1 N))
        const float sig = frcp(1.0f + fexp2(-0.1f*LOG2E*Ni));
        const float alpha = 0.3f*sig;
        const float beta  = 0.2f - 0.2f*sig;

        const float dd = Np1 - Ni;                        // exact -1/0/+1
        const float jump = (dd > 0.5f) ? dp : ((dd < -0.5f) ? dm : 0.0f);

        const float c = grad_bmm - (alpha*dp + beta*dm)*DTF
                      - 0.05f*DTF*gdx - 0.01f*DTF*ti + jump;
        C[ib] = c;
    }
}

// ---------------------------------------------------------------------------
// Final kernel: u_final = u0*s^32 + sum_i C_i*s^(31-i) is LINEAR -> the
// 32-step scan parallelizes across the 16 split-lanes with closed-form
// power weights; r-MLP split 16 ways; one shuffle-reduce.
// ---------------------------------------------------------------------------
__global__ __launch_bounds__(256) void final_kernel(
    const float* __restrict__ N, const float* __restrict__ X,
    const float* __restrict__ rW1, const float* __restrict__ rb1,
    const float* __restrict__ rW2, const float* __restrict__ rb2,
    const float* __restrict__ C, float* __restrict__ out)
{
    const int gid = blockIdx.x*256 + threadIdx.x;
    const int b = gid >> 4;          // batch element
    const int p = gid & 15;          // 16-way split

    const float n0 = N[b];
    const float x0 = X[(size_t)b*3 + 0], x1 = X[(size_t)b*3 + 1], x2 = X[(size_t)b*3 + 2];

    float accw = 0.f, accr = 0.f;
#pragma unroll
    for (int t = 0; t < 8; ++t) {
        const int j = p*8 + t;
        float pre = fmaf(rW1[j*4+0], n0, fmaf(rW1[j*4+1], x0,
                    fmaf(rW1[j*4+2], x1, fmaf(rW1[j*4+3], x2, rb1[j]))));
        float r  = frcp(1.0f + fexp2(SCALE*pre));
        float w2 = rW2[j];
        accw += w2;
        accr = fmaf(w2, r, accr);
    }

    // C combination: s = 1+0.05*DT; weights s^(31-i)
    const float l2s = 0.0022524617f;             // log2(1.0015625)
    const float wa = fexp2(l2s * (float)(31 - p));
    const float wb = fexp2(l2s * (float)(15 - p));
    float csum = fmaf(C[(size_t)p*BB + b], wa, C[(size_t)(p+16)*BB + b] * wb);

    accw += __shfl_down(accw, 8, 16);  accr += __shfl_down(accr, 8, 16);  csum += __shfl_down(csum, 8, 16);
    accw += __shfl_down(accw, 4, 16);  accr += __shfl_down(accr, 4, 16);  csum += __shfl_down(csum, 4, 16);
    accw += __shfl_down(accw, 2, 16);  accr += __shfl_down(accr, 2, 16);  csum += __shfl_down(csum, 2, 16);
    accw += __shfl_down(accw, 1, 16);  accr += __shfl_down(accr, 1, 16);  csum += __shfl_down(csum, 1, 16);

    if (p == 0) {
        float u0 = rb2[0] + accw - 2.0f*accr;    // rb2 + sum w2*tanh
        const float s32 = 1.05123007f;           // (1+0.05/32)^32
        out[b] = fmaf(u0, s32, csum);

        const int ibl = NSTEPS*BB + b;
        out[BB + b] = fmaf(0.1f, N[ibl], __cosf(X[(size_t)ibl*3]));
    }
}

// ---------------------------------------------------------------------------
extern "C" void kernel_launch(void* const* d_in, const int* in_sizes, int n_in,
                              void* d_out, int out_size, void* d_ws, size_t ws_size,
                              hipStream_t stream)
{
    const float* N   = (const float*)d_in[0];
    const float* X   = (const float*)d_in[1];
    const float* T   = (const float*)d_in[2];
    const float* dB  = (const float*)d_in[3];
    const float* rW1 = (const float*)d_in[4];
    const float* rb1 = (const float*)d_in[5];
    const float* rW2 = (const float*)d_in[6];
    const float* rb2 = (const float*)d_in[7];
    const float* gW1 = (const float*)d_in[8];
    const float* gb1 = (const float*)d_in[9];
    const float* gW2 = (const float*)d_in[10];
    const float* gb2 = (const float*)d_in[11];
    const float* jW1 = (const float*)d_in[12];
    const float* jb1 = (const float*)d_in[13];
    const float* jW2 = (const float*)d_in[14];
    // jb2 (d_in[15]) cancels in dp/dm — unused.

    float* ws   = (float*)d_ws;
    float* C    = ws;                                  // 32*16384 floats
    float* recA = ws + (size_t)NSTEPS*BB;              // 32*128*16 floats
    float* G    = recA + (size_t)NSTEPS*HH*16;         // 128 floats
    float* out  = (float*)d_out;

    xform_kernel<<<NSTEPS, HH, 0, stream>>>(gW1, gb1, gW2, gb2, jW1, jb1, jW2, recA, G);
    step_kernel<<<NSTEPS*(BB/64), 512, 0, stream>>>(N, X, T, dB, recA, G, C);
    final_kernel<<<BB*16/256, 256, 0, stream>>>(N, X, rW1, rb1, rW2, rb2, C, out);
}

// Round 11
// 63.942 us; speedup vs baseline: 1.1191x; 1.1191x over previous
//
#include <hip/hip_runtime.h>
#include <math.h>

#define BB 16384
#define NSTEPS 32
#define HH 128
#define DTF (1.0f/32.0f)
#define SCALE 2.88539008177792681f   // 2*log2(e):  e^{2x} = 2^{SCALE*x}
#define LOG2E 1.44269504088896340f

typedef float v2f  __attribute__((ext_vector_type(2)));
typedef float v16f __attribute__((ext_vector_type(16)));
typedef unsigned int v2u __attribute__((ext_vector_type(2)));

// compile-time slice: element-pair k of a v16f (even-aligned -> SGPR pair)
#define SL(v,k) (__builtin_shufflevector((v),(v),2*(k),2*(k)+1))

__device__ __forceinline__ v2f pk_fma(v2f a, v2f b, v2f c) {
    return __builtin_elementwise_fma(a, b, c);   // -> v_pk_fma_f32
}

// packed fast reciprocal: bit-trick estimate + 1 Newton. Valid x in [1, ~1e38].
__device__ __forceinline__ v2f pk_rcp1(v2f x) {
    v2u xb; __builtin_memcpy(&xb, &x, 8);
    v2u yb = (v2u){0x7EF311C3u, 0x7EF311C3u} - xb;
    v2f y;  __builtin_memcpy(&y, &yb, 8);
    v2f u = pk_fma(-x, y, (v2f){2.0f, 2.0f});    // 2 - x*y
    return y * u;
}

__device__ __forceinline__ float fexp2(float x) {
#if __has_builtin(__builtin_amdgcn_exp2f)
    return __builtin_amdgcn_exp2f(x);
#else
    float r; asm("v_exp_f32 %0, %1" : "=v"(r) : "v"(x)); return r;
#endif
}
__device__ __forceinline__ float frcp(float x) {
#if __has_builtin(__builtin_amdgcn_rcpf)
    return __builtin_amdgcn_rcpf(x);
#else
    float r; asm("v_rcp_f32 %0, %1" : "=v"(r) : "v"(x)); return r;
#endif
}
__device__ __forceinline__ float frsq(float x) {
#if __has_builtin(__builtin_amdgcn_rsqf)
    return __builtin_amdgcn_rsqf(x);
#else
    float r; asm("v_rsq_f32 %0, %1" : "=v"(r) : "v"(x)); return r;
#endif
}

// ---------------------------------------------------------------------------
// Transform kernel (R8 layout). Per unit-PAIR (j,j+1) at step i, 32 floats:
//  g-record [0..15]:  w0p w1p w2p w3p gbp g20p g21p g22p   (pairs, scaled)
//  j-record [16..31]: jw0p jw1p jw2p jw3p jbp jW2p cpp cmp
// ---------------------------------------------------------------------------
__global__ __launch_bounds__(HH) void xform_kernel(
    const float* __restrict__ gW1, const float* __restrict__ gb1,
    const float* __restrict__ gW2, const float* __restrict__ gb2,
    const float* __restrict__ jW1, const float* __restrict__ jb1,
    const float* __restrict__ jW2,
    float* __restrict__ recA, float* __restrict__ G)
{
    const int i = blockIdx.x;    // step
    const int j = threadIdx.x;   // hidden unit
    const int pair = j >> 1;
    const int ln   = j & 1;
    float* r = recA + ((size_t)i*64 + pair)*32;

    const float* gw = gW1 + (size_t)(i*HH + j)*4;
    const float* jw = jW1 + (size_t)(i*HH + j)*4;
    float jw0 = jw[0];
    float g20 = gW2[i*3*HH + 0*HH + j];
    float g21 = gW2[i*3*HH + 1*HH + j];
    float g22 = gW2[i*3*HH + 2*HH + j];

    r[ 0+ln] = SCALE*gw[0];
    r[ 2+ln] = SCALE*gw[1];
    r[ 4+ln] = SCALE*gw[2];
    r[ 6+ln] = SCALE*gw[3];
    r[ 8+ln] = SCALE*gb1[i*HH + j];
    r[10+ln] = -2.0f*g20;
    r[12+ln] = -2.0f*g21;
    r[14+ln] = -2.0f*g22;

    r[16+ln] = SCALE*jw0;
    r[18+ln] = SCALE*jw[1];
    r[20+ln] = SCALE*jw[2];
    r[22+ln] = SCALE*jw[3];
    r[24+ln] = SCALE*jb1[i*HH + j];
    r[26+ln] = -2.0f*jW2[i*HH + j];
    r[28+ln] = exp2f( SCALE*jw0);
    r[30+ln] = exp2f(-SCALE*jw0);

    __shared__ float sh[3*HH];
    sh[j] = g20; sh[HH + j] = g21; sh[2*HH + j] = g22;
    __syncthreads();
    for (int off = 64; off >= 1; off >>= 1) {
        if (j < off) {
            sh[j]      += sh[j + off];
            sh[HH + j] += sh[HH + j + off];
            sh[2*HH+j] += sh[2*HH + j + off];
        }
        __syncthreads();
    }
    if (j < 3) G[i*4 + j] = gb2[i*3 + j] + sh[j*HH];
}

// ---------------------------------------------------------------------------
// Main kernel (R8 optimum). Block = 256 = 64 batch slots x 4 j-quarters
// (jq wave-uniform via readfirstlane -> scalar weight loads). Each thread:
// 16 unit-pairs; packed operands are SGPR pairs (weights) or loop-invariant
// VGPR pairs (batch scalars). Quarters combine via LDS.
// Measured response surface: 2-way split 59.5us, 4-way 56.3us, 8-way 64.3us.
// ---------------------------------------------------------------------------
__global__ __launch_bounds__(256) void step_kernel(
    const float* __restrict__ N, const float* __restrict__ X,
    const float* __restrict__ T, const float* __restrict__ dB,
    const float* __restrict__ recA, const float* __restrict__ G,
    float* __restrict__ C)
{
    const int tid  = threadIdx.x;
    const int i    = blockIdx.x >> 8;          // step (block-uniform)
    const int bblk = blockIdx.x & 255;
    const int bl   = tid & 63;                 // local batch slot
    const int jq   = __builtin_amdgcn_readfirstlane(tid >> 6);  // quarter -> SGPR
    const int b    = bblk*64 + bl;
    const int ib   = i*BB + b;

    const float Ni = N[ib];
    const float x0 = X[(size_t)ib*3 + 0], x1 = X[(size_t)ib*3 + 1], x2 = X[(size_t)ib*3 + 2];

    // quarter q covers unit-pairs [q*16, q*16+16): 16 x 32 floats = 32 v16f
    const v16f* rec16 = (const v16f*)(recA + (size_t)i*HH*16 + (size_t)jq*512);

    const v2f Niv  = {Ni, Ni};
    const v2f x0v  = {x0, x0};
    const v2f x1v  = {x1, x1};
    const v2f x2v  = {x2, x2};
    const v2f onev = {1.0f, 1.0f};
    const v2f c25v = {25.0f, 25.0f};

    v2f ga0 = {0.f,0.f}, ga1 = {0.f,0.f}, ga2 = {0.f,0.f};
    v2f a0  = {0.f,0.f}, aP  = {0.f,0.f}, aM  = {0.f,0.f};

#pragma unroll 4
    for (int t = 0; t < 16; ++t) {
        const v16f Rg = rec16[2*t + 0];   // g-record
        const v16f Rj = rec16[2*t + 1];   // j-record

        // ---- g-MLP, units (2t, 2t+1) packed ----
        v2f ag = SL(Rg,4);
        ag = pk_fma(SL(Rg,0), Niv, ag);
        ag = pk_fma(SL(Rg,1), x0v, ag);
        ag = pk_fma(SL(Rg,2), x1v, ag);
        ag = pk_fma(SL(Rg,3), x2v, ag);
        ag = __builtin_elementwise_min(ag, c25v); // keep exp2 finite (rcp1 domain)
        v2f eg; eg.x = fexp2(ag.x); eg.y = fexp2(ag.y);
        v2f rg = pk_rcp1(eg + onev);
        ga0 = pk_fma(SL(Rg,5), rg, ga0);
        ga1 = pk_fma(SL(Rg,6), rg, ga1);
        ga2 = pk_fma(SL(Rg,7), rg, ga2);

        // ---- j-MLP, units (2t, 2t+1) packed, 3 N-shifts share one exp ----
        v2f aj = SL(Rj,4);
        aj = pk_fma(SL(Rj,0), Niv, aj);
        aj = pk_fma(SL(Rj,1), x0v, aj);
        aj = pk_fma(SL(Rj,2), x1v, aj);
        aj = pk_fma(SL(Rj,3), x2v, aj);
        aj = __builtin_elementwise_min(aj, c25v);
        v2f ej; ej.x = fexp2(aj.x); ej.y = fexp2(aj.y);
        v2f r0 = pk_rcp1(ej + onev);
        v2f rp = pk_rcp1(pk_fma(SL(Rj,6), ej, onev));
        v2f rm = pk_rcp1(pk_fma(SL(Rj,7), ej, onev));
        const v2f w2p = SL(Rj,5);
        a0 = pk_fma(w2p, r0, a0);
        aP = pk_fma(w2p, rp, aP);
        aM = pk_fma(w2p, rm, aM);
    }

    // horizontal: even+odd unit lanes
    const float hga0 = ga0.x + ga0.y;
    const float hga1 = ga1.x + ga1.y;
    const float hga2 = ga2.x + ga2.y;
    const float ha0  = a0.x  + a0.y;
    const float haP  = aP.x  + aP.y;
    const float haM  = aM.x  + aM.y;

    // combine 4 quarter-partials: quarters 1..3 write, quarter 0 reduces
    __shared__ float sh[3][6][64];
    if (jq) {
        float* s = &sh[jq-1][0][bl];
        s[0*64] = hga0; s[1*64] = hga1; s[2*64] = hga2;
        s[3*64] = ha0;  s[4*64] = haP;  s[5*64] = haM;
    }
    __syncthreads();
    if (!jq) {
        float v0 = hga0, v1 = hga1, v2 = hga2;
        float v3 = ha0,  v4 = haP,  v5 = haM;
#pragma unroll
        for (int q = 0; q < 3; ++q) {
            v0 += sh[q][0][bl]; v1 += sh[q][1][bl]; v2 += sh[q][2][bl];
            v3 += sh[q][3][bl]; v4 += sh[q][4][bl]; v5 += sh[q][5][bl];
        }
        const float g0 = G[i*4 + 0] + v0;
        const float g1 = G[i*4 + 1] + v1;
        const float g2 = G[i*4 + 2] + v2;

        const float Np1 = N[ib + BB];
        const float d0 = dB[(size_t)ib*3 + 0], d1 = dB[(size_t)ib*3 + 1], d2 = dB[(size_t)ib*3 + 2];
        const float ti = T[i];

        const float gdx = g0*x0 + g1*x1 + g2*x2;          // grad_u . x
        const float ss  = x0*x0 + x1*x1 + x2*x2;          // x . x
        const float gdB = g0*d0 + g1*d1 + g2*d2;          // grad_u . dB
        const float xdB = x0*d0 + x1*d1 + x2*d2;          // x . dB

        const float k = 1.41421356237309505f * frsq(fmaf(0.1f*Ni, Ni, 1.0f));
        // kg^T (I+o)(I-o) dB = k*(g.dB - (x.x)*(g.x)*(x.dB))
        const float grad_bmm = k * (gdB - ss*gdx*xdB);

        const float dp = v4 - v3;
        const float dm = v5 - v3;

        // alpha = 0.3*sig(0.1 N), beta = 0.2*(1-sig(0.1 N))
        const float sig = frcp(1.0f + fexp2(-0.1f*LOG2E*Ni));
        const float alpha = 0.3f*sig;
        const float beta  = 0.2f - 0.2f*sig;

        const float dd = Np1 - Ni;                        // exact -1/0/+1
        const float jump = (dd > 0.5f) ? dp : ((dd < -0.5f) ? dm : 0.0f);

        const float c = grad_bmm - (alpha*dp + beta*dm)*DTF
                      - 0.05f*DTF*gdx - 0.01f*DTF*ti + jump;
        C[ib] = c;
    }
}

// ---------------------------------------------------------------------------
// Final kernel: u_final = u0*s^32 + sum_i C_i*s^(31-i) is LINEAR -> the
// 32-step scan parallelizes across the 16 split-lanes with closed-form
// power weights; r-MLP split 16 ways; one shuffle-reduce.
// ---------------------------------------------------------------------------
__global__ __launch_bounds__(256) void final_kernel(
    const float* __restrict__ N, const float* __restrict__ X,
    const float* __restrict__ rW1, const float* __restrict__ rb1,
    const float* __restrict__ rW2, const float* __restrict__ rb2,
    const float* __restrict__ C, float* __restrict__ out)
{
    const int gid = blockIdx.x*256 + threadIdx.x;
    const int b = gid >> 4;          // batch element
    const int p = gid & 15;          // 16-way split

    const float n0 = N[b];
    const float x0 = X[(size_t)b*3 + 0], x1 = X[(size_t)b*3 + 1], x2 = X[(size_t)b*3 + 2];

    float accw = 0.f, accr = 0.f;
#pragma unroll
    for (int t = 0; t < 8; ++t) {
        const int j = p*8 + t;
        float pre = fmaf(rW1[j*4+0], n0, fmaf(rW1[j*4+1], x0,
                    fmaf(rW1[j*4+2], x1, fmaf(rW1[j*4+3], x2, rb1[j]))));
        float r  = frcp(1.0f + fexp2(SCALE*pre));
        float w2 = rW2[j];
        accw += w2;
        accr = fmaf(w2, r, accr);
    }

    // C combination: s = 1+0.05*DT; weights s^(31-i)
    const float l2s = 0.0022524617f;             // log2(1.0015625)
    const float wa = fexp2(l2s * (float)(31 - p));
    const float wb = fexp2(l2s * (float)(15 - p));
    float csum = fmaf(C[(size_t)p*BB + b], wa, C[(size_t)(p+16)*BB + b] * wb);

    accw += __shfl_down(accw, 8, 16);  accr += __shfl_down(accr, 8, 16);  csum += __shfl_down(csum, 8, 16);
    accw += __shfl_down(accw, 4, 16);  accr += __shfl_down(accr, 4, 16);  csum += __shfl_down(csum, 4, 16);
    accw += __shfl_down(accw, 2, 16);  accr += __shfl_down(accr, 2, 16);  csum += __shfl_down(csum, 2, 16);
    accw += __shfl_down(accw, 1, 16);  accr += __shfl_down(accr, 1, 16);  csum += __shfl_down(csum, 1, 16);

    if (p == 0) {
        float u0 = rb2[0] + accw - 2.0f*accr;    // rb2 + sum w2*tanh
        const float s32 = 1.05123007f;           // (1+0.05/32)^32
        out[b] = fmaf(u0, s32, csum);

        const int ibl = NSTEPS*BB + b;
        out[BB + b] = fmaf(0.1f, N[ibl], __cosf(X[(size_t)ibl*3]));
    }
}

// ---------------------------------------------------------------------------
extern "C" void kernel_launch(void* const* d_in, const int* in_sizes, int n_in,
                              void* d_out, int out_size, void* d_ws, size_t ws_size,
                              hipStream_t stream)
{
    const float* N   = (const float*)d_in[0];
    const float* X   = (const float*)d_in[1];
    const float* T   = (const float*)d_in[2];
    const float* dB  = (const float*)d_in[3];
    const float* rW1 = (const float*)d_in[4];
    const float* rb1 = (const float*)d_in[5];
    const float* rW2 = (const float*)d_in[6];
    const float* rb2 = (const float*)d_in[7];
    const float* gW1 = (const float*)d_in[8];
    const float* gb1 = (const float*)d_in[9];
    const float* gW2 = (const float*)d_in[10];
    const float* gb2 = (const float*)d_in[11];
    const float* jW1 = (const float*)d_in[12];
    const float* jb1 = (const float*)d_in[13];
    const float* jW2 = (const float*)d_in[14];
    // jb2 (d_in[15]) cancels in dp/dm — unused.

    float* ws   = (float*)d_ws;
    float* C    = ws;                                  // 32*16384 floats
    float* recA = ws + (size_t)NSTEPS*BB;              // 32*128*16 floats
    float* G    = recA + (size_t)NSTEPS*HH*16;         // 128 floats
    float* out  = (float*)d_out;

    xform_kernel<<<NSTEPS, HH, 0, stream>>>(gW1, gb1, gW2, gb2, jW1, jb1, jW2, recA, G);
    step_kernel<<<NSTEPS*(BB/64), 256, 0, stream>>>(N, X, T, dB, recA, G, C);
    final_kernel<<<BB*16/256, 256, 0, stream>>>(N, X, rW1, rb1, rW2, rb2, C, out);
}